// Round 1
// baseline (230.016 us; speedup 1.0000x reference)
//
#include <hip/hip_runtime.h>
#include <hip/hip_bf16.h>

#define I_DIM  512
#define O_DIM  512
#define NBATCH 1024
#define NSPL   8            // spline coeffs per input channel
#define KPI    12           // K slots per input channel: 8 spline + s_hi,s_hi,s_lo,0
#define KDIM   (I_DIM * KPI)   // 6144
#define NGRID  12           // extended grid points per channel

typedef __attribute__((ext_vector_type(8))) short bf16x8;
typedef __attribute__((ext_vector_type(4))) float f32x4;

// ---------------------------------------------------------------------------
// Wt[o][i*12+slot] bf16: slots 0..7 = sp*coef[k]; 8 = hi(sb); 9 = lo(sb); 10 = hi(sb); 11 = 0
// Paired with features slots [B0..B7, s_hi, s_hi, s_lo, 0]:
//   s_hi*w_hi + s_hi*w_lo + s_lo*w_hi  ~= s*sb  (rel err ~2^-17)
// ---------------------------------------------------------------------------
__global__ void build_wt_kernel(const float* __restrict__ coef,
                                const float* __restrict__ sb,
                                const float* __restrict__ sp,
                                __hip_bfloat16* __restrict__ Wt) {
    int tid = blockIdx.x * blockDim.x + threadIdx.x;  // tid = o*512 + i
    int i = tid & (I_DIM - 1);
    int o = tid >> 9;
    float sbv = sb[i * O_DIM + o];
    float spv = sp[i * O_DIM + o];
    const float* cf = coef + (size_t)(i * O_DIM + o) * NSPL;
    __align__(16) __hip_bfloat16 row[KPI];
#pragma unroll
    for (int k = 0; k < NSPL; ++k) row[k] = __float2bfloat16(spv * cf[k]);
    __hip_bfloat16 whi = __float2bfloat16(sbv);
    __hip_bfloat16 wlo = __float2bfloat16(sbv - __bfloat162float(whi));
    row[8]  = whi;
    row[9]  = wlo;
    row[10] = whi;
    row[11] = __float2bfloat16(0.0f);
    uint2* dst = (uint2*)(Wt + (size_t)o * KDIM + i * KPI);  // 24B per (o,i), coalesced in i
    const uint2* src = (const uint2*)row;
    dst[0] = src[0]; dst[1] = src[1]; dst[2] = src[2];
}

// ---------------------------------------------------------------------------
// Features: F[b][i*12+slot] bf16 = [B0..B7, s_hi, s_hi, s_lo, 0]
// Also zero-inits the layer's output buffer (re-poisoned to 0xAA each call).
// ---------------------------------------------------------------------------
__global__ void build_features_kernel(const float* __restrict__ x,
                                      const float* __restrict__ grid,
                                      __hip_bfloat16* __restrict__ F,
                                      float* __restrict__ out_zero) {
    int tid = blockIdx.x * blockDim.x + threadIdx.x;  // tid = b*512 + i
    out_zero[tid] = 0.0f;                              // BATCH*O_DIM == BATCH*I_DIM
    int i = tid & (I_DIM - 1);
    float xv = x[tid];

    float g[NGRID];
#pragma unroll
    for (int j = 0; j < NGRID; ++j) g[j] = grid[i * NGRID + j];

    float B[NGRID - 1];
#pragma unroll
    for (int j = 0; j < NGRID - 1; ++j)
        B[j] = (xv >= g[j] && xv < g[j + 1]) ? 1.0f : 0.0f;
#pragma unroll
    for (int p = 1; p <= 3; ++p) {
#pragma unroll
        for (int j = 0; j < NGRID - 1 - p; ++j) {
            B[j] = (xv - g[j]) / (g[j + p] - g[j]) * B[j]
                 + (g[j + p + 1] - xv) / (g[j + p + 1] - g[j + 1]) * B[j + 1];
        }
    }

    float s = xv / (1.0f + __expf(-xv));  // silu
    __hip_bfloat16 shi = __float2bfloat16(s);
    __hip_bfloat16 slo = __float2bfloat16(s - __bfloat162float(shi));

    __align__(16) __hip_bfloat16 row[KPI];
#pragma unroll
    for (int k = 0; k < NSPL; ++k) row[k] = __float2bfloat16(B[k]);
    row[8]  = shi;
    row[9]  = shi;
    row[10] = slo;
    row[11] = __float2bfloat16(0.0f);

    uint2* dst = (uint2*)(F + (size_t)tid * KPI);  // 24B per (b,i), coalesced
    const uint2* src = (const uint2*)row;
    dst[0] = src[0]; dst[1] = src[1]; dst[2] = src[2];
}

// ---------------------------------------------------------------------------
// GEMM: out[b,o] += sum_k F[b,k] * Wt[o][k]   (bf16 MFMA, fp32 acc)
// 64x64 tile, BK=64, 4 waves x (32x32 quadrant = 2x2 of 16x16x32), split-K=4.
// ---------------------------------------------------------------------------
#define BM 64
#define BN 64
#define BKK 64
#define SPLITK 4
#define KSEG (KDIM / SPLITK)   // 1536
#define LDK (BKK + 8)          // +8 bf16 pad: 2-way bank aliasing only (free)

__global__ __launch_bounds__(256)
void gemm_kernel(const __hip_bfloat16* __restrict__ A,   // [NBATCH][KDIM]
                 const __hip_bfloat16* __restrict__ Wt,  // [O_DIM][KDIM]
                 float* __restrict__ out) {              // [NBATCH][O_DIM]
    __shared__ __hip_bfloat16 lA[BM * LDK];
    __shared__ __hip_bfloat16 lB[BN * LDK];

    int bm = blockIdx.x;        // 0..15
    int bn = blockIdx.y;        // 0..7
    int ks = blockIdx.z;        // 0..SPLITK-1
    int tid = threadIdx.x;      // 0..255
    int lane = tid & 63;
    int wave = tid >> 6;
    int wr = (wave & 1) * 32;   // wave row offset in tile
    int wc = (wave >> 1) * 32;  // wave col offset in tile
    int q  = lane >> 4;         // quad 0..3
    int ln = lane & 15;

    f32x4 acc[2][2];
#pragma unroll
    for (int a = 0; a < 2; ++a)
#pragma unroll
        for (int b = 0; b < 2; ++b) acc[a][b] = (f32x4){0.f, 0.f, 0.f, 0.f};

    int lrow = tid >> 2;        // 0..63 staging row
    int lcg  = tid & 3;         // 0..3  staging 32B chunk
    const __hip_bfloat16* Ag = A  + (size_t)(bm * BM + lrow) * KDIM + ks * KSEG;
    const __hip_bfloat16* Bg = Wt + (size_t)(bn * BN + lrow) * KDIM + ks * KSEG;

    for (int kt = 0; kt < KSEG; kt += BKK) {
        __syncthreads();
        uint4 a0 = *(const uint4*)(Ag + kt + lcg * 16);
        uint4 a1 = *(const uint4*)(Ag + kt + lcg * 16 + 8);
        uint4 b0 = *(const uint4*)(Bg + kt + lcg * 16);
        uint4 b1 = *(const uint4*)(Bg + kt + lcg * 16 + 8);
        *(uint4*)(lA + lrow * LDK + lcg * 16)     = a0;
        *(uint4*)(lA + lrow * LDK + lcg * 16 + 8) = a1;
        *(uint4*)(lB + lrow * LDK + lcg * 16)     = b0;
        *(uint4*)(lB + lrow * LDK + lcg * 16 + 8) = b1;
        __syncthreads();

#pragma unroll
        for (int kh = 0; kh < 2; ++kh) {
            bf16x8 af[2], bfr[2];
            af[0]  = *(const bf16x8*)(lA + (wr + ln)      * LDK + kh * 32 + q * 8);
            af[1]  = *(const bf16x8*)(lA + (wr + 16 + ln) * LDK + kh * 32 + q * 8);
            bfr[0] = *(const bf16x8*)(lB + (wc + ln)      * LDK + kh * 32 + q * 8);
            bfr[1] = *(const bf16x8*)(lB + (wc + 16 + ln) * LDK + kh * 32 + q * 8);
#pragma unroll
            for (int rt = 0; rt < 2; ++rt)
#pragma unroll
                for (int ct = 0; ct < 2; ++ct)
                    acc[rt][ct] = __builtin_amdgcn_mfma_f32_16x16x32_bf16(
                        af[rt], bfr[ct], acc[rt][ct], 0, 0, 0);
        }
    }

    // epilogue: C/D layout col = lane&15, row = quad*4 + reg
    int orow = bm * BM + wr;
    int ocol = bn * BN + wc + ln;
#pragma unroll
    for (int rt = 0; rt < 2; ++rt)
#pragma unroll
        for (int ct = 0; ct < 2; ++ct)
#pragma unroll
            for (int r = 0; r < 4; ++r)
                atomicAdd(out + (size_t)(orow + rt * 16 + q * 4 + r) * O_DIM
                              + ocol + ct * 16,
                          acc[rt][ct][r]);
}

// ---------------------------------------------------------------------------
extern "C" void kernel_launch(void* const* d_in, const int* in_sizes, int n_in,
                              void* d_out, int out_size, void* d_ws, size_t ws_size,
                              hipStream_t stream) {
    const float* x0      = (const float*)d_in[0];
    const float* grid[3] = {(const float*)d_in[1], (const float*)d_in[5], (const float*)d_in[9]};
    const float* coef[3] = {(const float*)d_in[2], (const float*)d_in[6], (const float*)d_in[10]};
    const float* sb[3]   = {(const float*)d_in[3], (const float*)d_in[7], (const float*)d_in[11]};
    const float* sp[3]   = {(const float*)d_in[4], (const float*)d_in[8], (const float*)d_in[12]};

    char* ws = (char*)d_ws;
    const size_t wt_bytes = (size_t)O_DIM * KDIM * sizeof(__hip_bfloat16);   // 6 291 456
    const size_t f_bytes  = (size_t)NBATCH * KDIM * sizeof(__hip_bfloat16);  // 12 582 912
    __hip_bfloat16* Wt[3];
    for (int l = 0; l < 3; ++l) Wt[l] = (__hip_bfloat16*)(ws + (size_t)l * wt_bytes);
    __hip_bfloat16* F = (__hip_bfloat16*)(ws + 3 * wt_bytes);
    float* x1 = (float*)(ws + 3 * wt_bytes + f_bytes);
    float* x2 = x1 + (size_t)NBATCH * O_DIM;

    for (int l = 0; l < 3; ++l)
        build_wt_kernel<<<(I_DIM * O_DIM) / 256, 256, 0, stream>>>(coef[l], sb[l], sp[l], Wt[l]);

    const float* xin = x0;
    float* xout[3] = {x1, x2, (float*)d_out};
    for (int l = 0; l < 3; ++l) {
        build_features_kernel<<<(NBATCH * I_DIM) / 256, 256, 0, stream>>>(xin, grid[l], F, xout[l]);
        gemm_kernel<<<dim3(16, 8, SPLITK), 256, 0, stream>>>(F, Wt[l], xout[l]);
        xin = xout[l];
    }
}

// Round 2
// 201.338 us; speedup vs baseline: 1.1424x; 1.1424x over previous
//
#include <hip/hip_runtime.h>
#include <hip/hip_bf16.h>

#define I_DIM  512
#define O_DIM  512
#define NBATCH 1024
#define NSPL   8            // spline coeffs per input channel
#define KPI    12           // K slots per input channel: 8 spline + s_hi,s_hi,s_lo,0
#define KDIM   (I_DIM * KPI)   // 6144
#define NGRID  12           // extended grid points per channel

typedef __attribute__((ext_vector_type(8))) short bf16x8;
typedef __attribute__((ext_vector_type(4))) float f32x4;

// ---------------------------------------------------------------------------
// async global->LDS 16B: dest = wave-uniform base + lane*16 (m97/m104 semantics)
// ---------------------------------------------------------------------------
__device__ __forceinline__ void gload_lds16(const __hip_bfloat16* g, __hip_bfloat16* l) {
    __builtin_amdgcn_global_load_lds(
        (const __attribute__((address_space(1))) void*)g,
        (__attribute__((address_space(3))) void*)l, 16, 0, 0);
}

// ---------------------------------------------------------------------------
// Wt[o][i*12+slot] bf16: slots 0..7 = sp*coef[k]; 8 = hi(sb); 9 = lo(sb); 10 = hi(sb); 11 = 0
// Paired with features [B0..B7, s_hi, s_hi, s_lo, 0]:
//   s_hi*w_hi + s_hi*w_lo + s_lo*w_hi ~= s*sb  (rel err ~2^-17)
// One kernel builds all 3 layers (blockIdx.y = layer).
// ---------------------------------------------------------------------------
__global__ void build_wt_all(const float* __restrict__ c0, const float* __restrict__ b0, const float* __restrict__ p0,
                             const float* __restrict__ c1, const float* __restrict__ b1, const float* __restrict__ p1,
                             const float* __restrict__ c2, const float* __restrict__ b2, const float* __restrict__ p2,
                             __hip_bfloat16* __restrict__ Wt) {
    int l = blockIdx.y;
    const float* coef = l == 0 ? c0 : (l == 1 ? c1 : c2);
    const float* sb   = l == 0 ? b0 : (l == 1 ? b1 : b2);
    const float* sp   = l == 0 ? p0 : (l == 1 ? p1 : p2);
    __hip_bfloat16* W = Wt + (size_t)l * O_DIM * KDIM;

    int tid = blockIdx.x * blockDim.x + threadIdx.x;  // tid = o*512 + i
    int i = tid & (I_DIM - 1);
    int o = tid >> 9;
    float sbv = sb[i * O_DIM + o];
    float spv = sp[i * O_DIM + o];
    const float* cf = coef + (size_t)(i * O_DIM + o) * NSPL;
    __align__(16) __hip_bfloat16 row[KPI];
#pragma unroll
    for (int k = 0; k < NSPL; ++k) row[k] = __float2bfloat16(spv * cf[k]);
    __hip_bfloat16 whi = __float2bfloat16(sbv);
    __hip_bfloat16 wlo = __float2bfloat16(sbv - __bfloat162float(whi));
    row[8]  = whi;
    row[9]  = wlo;
    row[10] = whi;
    row[11] = __float2bfloat16(0.0f);
    uint2* dst = (uint2*)(W + (size_t)o * KDIM + i * KPI);
    const uint2* src = (const uint2*)row;
    dst[0] = src[0]; dst[1] = src[1]; dst[2] = src[2];
}

// ---------------------------------------------------------------------------
// Feature build: F[b][i*12+slot] = [B0..B7, s_hi, s_hi, s_lo, 0] (bf16).
// x comes either from a dense fp32 array (layer 0) or from summing the
// SPLITK partial buffers of the previous GEMM (fused splitK reduction).
// ---------------------------------------------------------------------------
#define SPLITK 8

__device__ __forceinline__ void features_core(float xv, const float* __restrict__ grid,
                                              int i, __hip_bfloat16* __restrict__ dst) {
    float g[NGRID];
#pragma unroll
    for (int j = 0; j < NGRID; ++j) g[j] = grid[i * NGRID + j];

    float B[NGRID - 1];
#pragma unroll
    for (int j = 0; j < NGRID - 1; ++j)
        B[j] = (xv >= g[j] && xv < g[j + 1]) ? 1.0f : 0.0f;
#pragma unroll
    for (int p = 1; p <= 3; ++p) {
#pragma unroll
        for (int j = 0; j < NGRID - 1 - p; ++j) {
            B[j] = (xv - g[j]) / (g[j + p] - g[j]) * B[j]
                 + (g[j + p + 1] - xv) / (g[j + p + 1] - g[j + 1]) * B[j + 1];
        }
    }
    float s = xv / (1.0f + __expf(-xv));  // silu
    __hip_bfloat16 shi = __float2bfloat16(s);
    __hip_bfloat16 slo = __float2bfloat16(s - __bfloat162float(shi));

    __align__(16) __hip_bfloat16 row[KPI];
#pragma unroll
    for (int k = 0; k < NSPL; ++k) row[k] = __float2bfloat16(B[k]);
    row[8]  = shi;
    row[9]  = shi;
    row[10] = slo;
    row[11] = __float2bfloat16(0.0f);

    uint2* d = (uint2*)dst;
    const uint2* srow = (const uint2*)row;
    d[0] = srow[0]; d[1] = srow[1]; d[2] = srow[2];
}

__global__ void build_features_x(const float* __restrict__ x,
                                 const float* __restrict__ grid,
                                 __hip_bfloat16* __restrict__ F) {
    int tid = blockIdx.x * blockDim.x + threadIdx.x;  // b*512+i
    features_core(x[tid], grid, tid & (I_DIM - 1), F + (size_t)tid * KPI);
}

__global__ void build_features_sum(const float* __restrict__ P,  // [SPLITK][NBATCH*I_DIM]
                                   const float* __restrict__ grid,
                                   __hip_bfloat16* __restrict__ F) {
    int tid = blockIdx.x * blockDim.x + threadIdx.x;
    float xv = 0.f;
#pragma unroll
    for (int s = 0; s < SPLITK; ++s) xv += P[(size_t)s * NBATCH * I_DIM + tid];
    features_core(xv, grid, tid & (I_DIM - 1), F + (size_t)tid * KPI);
}

__global__ void reduce_out(const float* __restrict__ P, float* __restrict__ out) {
    int tid = blockIdx.x * blockDim.x + threadIdx.x;
    float v = 0.f;
#pragma unroll
    for (int s = 0; s < SPLITK; ++s) v += P[(size_t)s * NBATCH * O_DIM + tid];
    out[tid] = v;
}

// ---------------------------------------------------------------------------
// GEMM: P[ks][b,o] = sum_{k in seg ks} F[b,k] * Wt[o][k]   (bf16 MFMA, fp32 acc)
// m97-style: 64x64 tile, BK=64, global_load_lds width-16, XOR-swizzled LDS
// (unpadded rows of 128B; chunk j of row r stored at j^(r&7) -> 2-way bank
// aliasing only on ds_read_b128, which is free per m136). splitK=8 -> 1024
// blocks = 4 blocks/CU. Plain stores (no atomics); reduction fused downstream.
// ---------------------------------------------------------------------------
#define BM 64
#define BN 64
#define BK 64                  // bf16 elems per row; 128 B
#define KSEG (KDIM / SPLITK)   // 768

__global__ __launch_bounds__(256)
void gemm_kernel(const __hip_bfloat16* __restrict__ A,   // [NBATCH][KDIM]
                 const __hip_bfloat16* __restrict__ Wt,  // [O_DIM][KDIM]
                 float* __restrict__ P) {                // [SPLITK][NBATCH][O_DIM]
    __shared__ __hip_bfloat16 lA[BM * BK];   // 8 KB, no pad (global_load_lds dest)
    __shared__ __hip_bfloat16 lB[BN * BK];   // 8 KB

    int bm = blockIdx.x;        // 0..15
    int bn = blockIdx.y;        // 0..7
    int ks = blockIdx.z;        // 0..7
    int tid = threadIdx.x;
    int lane = tid & 63;
    int wave = tid >> 6;
    int wr = (wave & 1) * 32;
    int wc = (wave >> 1) * 32;
    int q  = lane >> 4;         // 0..3
    int ln = lane & 15;

    f32x4 acc[2][2];
#pragma unroll
    for (int a = 0; a < 2; ++a)
#pragma unroll
        for (int b = 0; b < 2; ++b) acc[a][b] = (f32x4){0.f, 0.f, 0.f, 0.f};

    const __hip_bfloat16* Abase = A  + (size_t)(bm * BM) * KDIM + ks * KSEG;
    const __hip_bfloat16* Bbase = Wt + (size_t)(bn * BN) * KDIM + ks * KSEG;

    // staging: chunk cc (16B) of tile; row r = cc>>3, swizzled pos jp = cc&7,
    // source chunk j = jp ^ (r&7). Each wave: 2 calls x 64 lanes covers 128
    // chunks (16 rows) of A and of B.
    int cc0 = wave * 128 + lane;          // call 0 chunk
    int cc1 = cc0 + 64;                   // call 1 chunk
    int r0 = cc0 >> 3, j0 = (cc0 & 7) ^ (r0 & 7);
    int r1 = cc1 >> 3, j1 = (cc1 & 7) ^ (r1 & 7);
    __hip_bfloat16* ldsA0 = lA + (size_t)(wave * 128) * 8;
    __hip_bfloat16* ldsA1 = lA + (size_t)(wave * 128 + 64) * 8;
    __hip_bfloat16* ldsB0 = lB + (size_t)(wave * 128) * 8;
    __hip_bfloat16* ldsB1 = lB + (size_t)(wave * 128 + 64) * 8;

    for (int kt = 0; kt < KSEG; kt += BK) {
        __syncthreads();
        gload_lds16(Abase + (size_t)r0 * KDIM + kt + j0 * 8, ldsA0);
        gload_lds16(Abase + (size_t)r1 * KDIM + kt + j1 * 8, ldsA1);
        gload_lds16(Bbase + (size_t)r0 * KDIM + kt + j0 * 8, ldsB0);
        gload_lds16(Bbase + (size_t)r1 * KDIM + kt + j1 * 8, ldsB1);
        __syncthreads();   // compiler emits vmcnt(0) drain before s_barrier

#pragma unroll
        for (int kh = 0; kh < 2; ++kh) {
            bf16x8 af[2], bfr[2];
#pragma unroll
            for (int rt = 0; rt < 2; ++rt) {
                int row = wr + rt * 16 + ln;
                af[rt] = *(const bf16x8*)(lA + row * BK + (((kh * 4 + q) ^ (row & 7)) * 8));
            }
#pragma unroll
            for (int ct = 0; ct < 2; ++ct) {
                int row = wc + ct * 16 + ln;
                bfr[ct] = *(const bf16x8*)(lB + row * BK + (((kh * 4 + q) ^ (row & 7)) * 8));
            }
#pragma unroll
            for (int rt = 0; rt < 2; ++rt)
#pragma unroll
                for (int ct = 0; ct < 2; ++ct)
                    acc[rt][ct] = __builtin_amdgcn_mfma_f32_16x16x32_bf16(
                        af[rt], bfr[ct], acc[rt][ct], 0, 0, 0);
        }
    }

    // epilogue: C/D layout col = lane&15, row = quad*4 + reg (round-0 verified)
    float* Pp = P + (size_t)ks * NBATCH * O_DIM;
    int orow = bm * BM + wr;
    int ocol = bn * BN + wc + ln;
#pragma unroll
    for (int rt = 0; rt < 2; ++rt)
#pragma unroll
        for (int ct = 0; ct < 2; ++ct)
#pragma unroll
            for (int r = 0; r < 4; ++r)
                Pp[(size_t)(orow + rt * 16 + q * 4 + r) * O_DIM + ocol + ct * 16]
                    = acc[rt][ct][r];
}

// ---------------------------------------------------------------------------
extern "C" void kernel_launch(void* const* d_in, const int* in_sizes, int n_in,
                              void* d_out, int out_size, void* d_ws, size_t ws_size,
                              hipStream_t stream) {
    const float* x0      = (const float*)d_in[0];
    const float* grid[3] = {(const float*)d_in[1], (const float*)d_in[5], (const float*)d_in[9]};
    const float* coef[3] = {(const float*)d_in[2], (const float*)d_in[6], (const float*)d_in[10]};
    const float* sb[3]   = {(const float*)d_in[3], (const float*)d_in[7], (const float*)d_in[11]};
    const float* sp[3]   = {(const float*)d_in[4], (const float*)d_in[8], (const float*)d_in[12]};

    char* ws = (char*)d_ws;
    const size_t wt_bytes = (size_t)O_DIM * KDIM * sizeof(__hip_bfloat16);   // 6.3 MB/layer
    const size_t f_bytes  = (size_t)NBATCH * KDIM * sizeof(__hip_bfloat16);  // 12.6 MB
    __hip_bfloat16* Wt = (__hip_bfloat16*)ws;                  // 3 layers contiguous
    __hip_bfloat16* F  = (__hip_bfloat16*)(ws + 3 * wt_bytes);
    float* P = (float*)(ws + 3 * wt_bytes + f_bytes);          // [SPLITK][1024][512] = 16.8 MB

    build_wt_all<<<dim3((I_DIM * O_DIM) / 256, 3), 256, 0, stream>>>(
        coef[0], sb[0], sp[0], coef[1], sb[1], sp[1], coef[2], sb[2], sp[2], Wt);

    build_features_x<<<(NBATCH * I_DIM) / 256, 256, 0, stream>>>(x0, grid[0], F);
    gemm_kernel<<<dim3(16, 8, SPLITK), 256, 0, stream>>>(F, Wt, P);

    for (int l = 1; l < 3; ++l) {
        build_features_sum<<<(NBATCH * I_DIM) / 256, 256, 0, stream>>>(P, grid[l], F);
        gemm_kernel<<<dim3(16, 8, SPLITK), 256, 0, stream>>>(F, Wt + (size_t)l * O_DIM * KDIM, P);
    }
    reduce_out<<<(NBATCH * O_DIM) / 256, 256, 0, stream>>>(P, (float*)d_out);
}